// Round 2
// baseline (2260.046 us; speedup 1.0000x reference)
//
#include <hip/hip_runtime.h>
#include <stdint.h>

#define N_ROWS 32768
#define D_DIM  512
#define K_CODES 4096

// ---- workspace layout (bytes) ----
// keys   : [0, 262144)           u64[32768]
// xnorm  : [262144, 393216)      f32[32768]
// enorm  : [393216, 409600)      f32[4096]
// lossAcc: [409600, 409616)      double (+pad)
// embT   : [409616, +8 MiB)      f32[4096][512]
#define WS_KEYS   0
#define WS_XNORM  262144
#define WS_ENORM  393216
#define WS_LOSS   409600
#define WS_EMBT   409616

__global__ __launch_bounds__(256) void k_init(unsigned long long* keys, double* lossAcc) {
    int t = blockIdx.x * 256 + threadIdx.x;
    if (t < N_ROWS) keys[t] = ~0ull;
    if (t == 0) *lossAcc = 0.0;
}

// emb [D][K] -> embT [K][D] (coalesced gather later); values copied bitwise
__global__ __launch_bounds__(256) void k_transpose(const float* __restrict__ emb,
                                                   float* __restrict__ embT) {
    __shared__ float tile[64][65];
    int k0 = blockIdx.x * 64;
    int d0 = blockIdx.y * 64;
    int tid = threadIdx.x;
    int kk = tid & 63;
    int dd = tid >> 6;
#pragma unroll
    for (int r = 0; r < 16; ++r) {
        int d = dd + r * 4;
        tile[d][kk] = emb[(size_t)(d0 + d) * K_CODES + k0 + kk];
    }
    __syncthreads();
    int dOff = tid & 63;
    int kBase = tid >> 6;
#pragma unroll
    for (int r = 0; r < 16; ++r) {
        int k = kBase + r * 4;
        embT[(size_t)(k0 + k) * D_DIM + d0 + dOff] = tile[dOff][k];
    }
}

// xnorm[row] = np.sum(x*x, axis=1) replicated bitwise:
// pairwise 512 -> (B0+B1)+(B2+B3); each 128-block via numpy AVX512 npyv path:
//   V[l]  = ((p[l]+p[16+l])+(p[32+l]+p[48+l])) + ((p[64+l]+p[80+l])+(p[96+l]+p[112+l]))
//   T1[m] = V[m]+V[m+8]; T2[m] = T1[m]+T1[m+4]; B = (T2[0]+T2[2])+(T2[1]+T2[3])
// fp add is bitwise-commutative, so the shfl_xor butterfly reproduces the tree.
__global__ __launch_bounds__(256) void k_xnorm(const float* __restrict__ x,
                                               float* __restrict__ xnorm) {
#pragma clang fp contract(off)
    int lane = threadIdx.x & 63;
    int l = lane & 15;          // vector lane 0..15
    int rowInWave = lane >> 4;  // 0..3
    int wave = blockIdx.x * 4 + (threadIdx.x >> 6);
    int row = wave * 4 + rowInWave;
    const float* xr = x + (size_t)row * D_DIM;
    float B[4];
#pragma unroll
    for (int b = 0; b < 4; ++b) {
        const float* a = xr + b * 128;
        float r[8];
#pragma unroll
        for (int j = 0; j < 8; ++j) {
            float v = a[j * 16 + l];
            r[j] = v * v;
        }
        float V = ((r[0] + r[1]) + (r[2] + r[3])) + ((r[4] + r[5]) + (r[6] + r[7]));
        float T1 = V + __shfl_xor(V, 8);
        float T2 = T1 + __shfl_xor(T1, 4);
        float U  = T2 + __shfl_xor(T2, 2);
        B[b] = U + __shfl_xor(U, 1);
    }
    float total = (B[0] + B[1]) + (B[2] + B[3]);
    if (l == 0) xnorm[row] = total;
}

// enorm[k] = np.sum(e*e, axis=0): outer-axis reduce = strictly sequential over d.
__global__ __launch_bounds__(256) void k_enorm(const float* __restrict__ emb,
                                               float* __restrict__ enorm) {
#pragma clang fp contract(off)
    int k = blockIdx.x * 256 + threadIdx.x;
    float v = emb[k];
    float acc = v * v;
    for (int d = 1; d < D_DIM; ++d) {
        float u = emb[(size_t)d * K_CODES + k];
        acc = acc + u * u;  // rounded product, then plain add (no fma) == numpy
    }
    enorm[k] = acc;
}

// Fused GEMM + argmin. Block tile 128 rows x 64 codes, 256 threads, 8x4/thread.
// acc accumulates a SINGLE sequential fp32 FMA chain over d=0..511 ascending —
// bitwise identical to BLAS sgemm's per-element k-chain.
// d = fl(fl(xnorm+enorm) - 2*acc) replicates the reference formula's roundings.
__global__ __launch_bounds__(256) void k_argmin(const float* __restrict__ x,
                                                const float* __restrict__ emb,
                                                const float* __restrict__ xnorm,
                                                const float* __restrict__ enorm,
                                                unsigned long long* __restrict__ keys) {
    __shared__ float As[16][128];  // [d][m]
    __shared__ float Bs[16][64];   // [d][n]
    const int tid = threadIdx.x;
    const int tx = tid & 15;
    const int ty = tid >> 4;
    const int rowBase = blockIdx.x * 128;
    const int colBase = blockIdx.y * 64;

    float acc[8][4];
#pragma unroll
    for (int j = 0; j < 8; ++j)
#pragma unroll
        for (int i = 0; i < 4; ++i) acc[j][i] = 0.f;

    const int lr  = tid >> 2;
    const int ld4 = (tid & 3) * 4;
    const int bd  = tid >> 4;
    const int bk4 = (tid & 15) * 4;

    for (int dc = 0; dc < D_DIM; dc += 16) {
        __syncthreads();
        float4 a0 = *(const float4*)&x[(size_t)(rowBase + lr) * D_DIM + dc + ld4];
        float4 a1 = *(const float4*)&x[(size_t)(rowBase + lr + 64) * D_DIM + dc + ld4];
        As[ld4 + 0][lr] = a0.x; As[ld4 + 1][lr] = a0.y;
        As[ld4 + 2][lr] = a0.z; As[ld4 + 3][lr] = a0.w;
        As[ld4 + 0][lr + 64] = a1.x; As[ld4 + 1][lr + 64] = a1.y;
        As[ld4 + 2][lr + 64] = a1.z; As[ld4 + 3][lr + 64] = a1.w;
        float4 b = *(const float4*)&emb[(size_t)(dc + bd) * K_CODES + colBase + bk4];
        *(float4*)&Bs[bd][bk4] = b;
        __syncthreads();
#pragma unroll
        for (int d = 0; d < 16; ++d) {
            float4 av0 = *(const float4*)&As[d][ty * 8];
            float4 av1 = *(const float4*)&As[d][ty * 8 + 4];
            float aa[8] = {av0.x, av0.y, av0.z, av0.w, av1.x, av1.y, av1.z, av1.w};
            float bb[4] = {Bs[d][tx], Bs[d][tx + 16], Bs[d][tx + 32], Bs[d][tx + 48]};
#pragma unroll
            for (int j = 0; j < 8; ++j)
#pragma unroll
                for (int i = 0; i < 4; ++i)
                    acc[j][i] = fmaf(aa[j], bb[i], acc[j][i]);
        }
    }

    float en[4];
#pragma unroll
    for (int i = 0; i < 4; ++i) en[i] = enorm[colBase + tx + 16 * i];
#pragma unroll
    for (int j = 0; j < 8; ++j) {
        float A = xnorm[rowBase + ty * 8 + j];
        unsigned long long best = ~0ull;
#pragma unroll
        for (int i = 0; i < 4; ++i) {
            float t1 = A + en[i];                 // fl(xnorm + enorm)
            float dd = t1 - 2.0f * acc[j][i];     // fl(t1 - 2*sim); 2*sim exact
            unsigned u = __float_as_uint(dd);
            u = (u & 0x80000000u) ? ~u : (u | 0x80000000u);
            unsigned long long key =
                ((unsigned long long)u << 32) | (unsigned)(colBase + tx + 16 * i);
            best = key < best ? key : best;
        }
#pragma unroll
        for (int off = 8; off > 0; off >>= 1) {
            unsigned long long other = __shfl_xor(best, off, 16);
            best = other < best ? other : best;
        }
        if (tx == 0) atomicMin(&keys[rowBase + ty * 8 + j], best);
    }
}

// gather codes, STE output fl(x + fl(q-x)), loss partials in f64
__global__ __launch_bounds__(256) void k_gather(const float* __restrict__ x,
                                                const float* __restrict__ embSrc,
                                                int embIsT,
                                                const unsigned long long* __restrict__ keys,
                                                float* __restrict__ out,
                                                double* __restrict__ lossAcc) {
#pragma clang fp contract(off)
    int tid = threadIdx.x;
    int row = blockIdx.x * 2 + (tid >> 7);
    int d = (tid & 127) * 4;
    int idx = (int)(keys[row] & 0xFFFFFFFFull);
    float4 q;
    if (embIsT) {
        q = *(const float4*)&embSrc[(size_t)idx * D_DIM + d];
    } else {
        q.x = embSrc[(size_t)(d + 0) * K_CODES + idx];
        q.y = embSrc[(size_t)(d + 1) * K_CODES + idx];
        q.z = embSrc[(size_t)(d + 2) * K_CODES + idx];
        q.w = embSrc[(size_t)(d + 3) * K_CODES + idx];
    }
    float4 xv = *(const float4*)&x[(size_t)row * D_DIM + d];
    float d0 = q.x - xv.x, d1 = q.y - xv.y, d2 = q.z - xv.z, d3 = q.w - xv.w;
    float4 o;
    o.x = xv.x + d0; o.y = xv.y + d1; o.z = xv.z + d2; o.w = xv.w + d3;
    *(float4*)&out[(size_t)row * D_DIM + d] = o;
    float s0 = d0 * d0, s1 = d1 * d1, s2 = d2 * d2, s3 = d3 * d3;
    double s = ((double)s0 + (double)s1) + ((double)s2 + (double)s3);
#pragma unroll
    for (int off = 32; off > 0; off >>= 1) s += __shfl_xor(s, off, 64);
    __shared__ double wsum[4];
    int lane = tid & 63, wv = tid >> 6;
    if (lane == 0) wsum[wv] = s;
    __syncthreads();
    if (tid == 0) atomicAdd(lossAcc, (wsum[0] + wsum[1]) + (wsum[2] + wsum[3]));
}

__global__ void k_finalize(const double* lossAcc, float* out) {
    float m = (float)(*lossAcc / 16777216.0);  // mean((q-x)^2), N*D = 2^24
    out[(size_t)N_ROWS * D_DIM] = 0.25f * m + m;  // beta*m + m, rounded like np
}

extern "C" void kernel_launch(void* const* d_in, const int* in_sizes, int n_in,
                              void* d_out, int out_size, void* d_ws, size_t ws_size,
                              hipStream_t stream) {
    const float* x = (const float*)d_in[0];
    const float* emb = (const float*)d_in[1];
    float* out = (float*)d_out;
    char* ws = (char*)d_ws;

    unsigned long long* keys = (unsigned long long*)(ws + WS_KEYS);
    float* xnorm = (float*)(ws + WS_XNORM);
    float* enorm = (float*)(ws + WS_ENORM);
    double* lossAcc = (double*)(ws + WS_LOSS);
    float* embT = (float*)(ws + WS_EMBT);
    size_t need = WS_EMBT + (size_t)K_CODES * D_DIM * sizeof(float);
    int useT = (ws_size >= need) ? 1 : 0;

    hipLaunchKernelGGL(k_init, dim3(128), dim3(256), 0, stream, keys, lossAcc);
    if (useT)
        hipLaunchKernelGGL(k_transpose, dim3(K_CODES / 64, D_DIM / 64), dim3(256), 0, stream,
                           emb, embT);
    hipLaunchKernelGGL(k_xnorm, dim3(N_ROWS / 16), dim3(256), 0, stream, x, xnorm);
    hipLaunchKernelGGL(k_enorm, dim3(K_CODES / 256), dim3(256), 0, stream, emb, enorm);
    hipLaunchKernelGGL(k_argmin, dim3(N_ROWS / 128, K_CODES / 64), dim3(256), 0, stream,
                       x, emb, xnorm, enorm, keys);
    hipLaunchKernelGGL(k_gather, dim3(N_ROWS / 2), dim3(256), 0, stream,
                       x, useT ? embT : emb, useT, keys, out, lossAcc);
    hipLaunchKernelGGL(k_finalize, dim3(1), dim3(1), 0, stream, lossAcc, out);
}

// Round 4
// 1668.081 us; speedup vs baseline: 1.3549x; 1.3549x over previous
//
#include <hip/hip_runtime.h>
#include <stdint.h>

#define N_ROWS 32768
#define D_DIM  512
#define K_CODES 4096

// ---- workspace layout (bytes) ----
#define WS_KEYS   0          // u64[32768]            -> 262144
#define WS_XNORM  262144     // f32[32768]            -> 393216
#define WS_ENORM  393216     // f32[4096]             -> 409600
#define WS_PART   409600     // f32[16384]            -> 475136
#define WS_EMBT   475136     // f32[4096*512] = 8 MiB

typedef __attribute__((address_space(3))) unsigned int lds_uint;
typedef __attribute__((address_space(1))) const unsigned int glob_uint;
__device__ __forceinline__ void async_cp16(const void* g, void* l) {
    // 16B per lane, LDS dest = wave-uniform base + lane*16
    __builtin_amdgcn_global_load_lds((glob_uint*)g, (lds_uint*)l, 16, 0, 0);
}

__global__ __launch_bounds__(256) void k_init(unsigned long long* keys) {
    int t = blockIdx.x * 256 + threadIdx.x;
    if (t < N_ROWS) keys[t] = ~0ull;
}

// emb [D][K] -> embT [K][D] (bitwise copy, for coalesced gather)
__global__ __launch_bounds__(256) void k_transpose(const float* __restrict__ emb,
                                                   float* __restrict__ embT) {
    __shared__ float tile[64][65];
    int k0 = blockIdx.x * 64;
    int d0 = blockIdx.y * 64;
    int tid = threadIdx.x;
    int kk = tid & 63;
    int dd = tid >> 6;
#pragma unroll
    for (int r = 0; r < 16; ++r) {
        int d = dd + r * 4;
        tile[d][kk] = emb[(size_t)(d0 + d) * K_CODES + k0 + kk];
    }
    __syncthreads();
    int dOff = tid & 63;
    int kBase = tid >> 6;
#pragma unroll
    for (int r = 0; r < 16; ++r) {
        int k = kBase + r * 4;
        embT[(size_t)(k0 + k) * D_DIM + d0 + dOff] = tile[dOff][k];
    }
}

// xnorm = np.sum(x*x, axis=1), bitwise (numpy pairwise + AVX512 tree)
__global__ __launch_bounds__(256) void k_xnorm(const float* __restrict__ x,
                                               float* __restrict__ xnorm) {
#pragma clang fp contract(off)
    int lane = threadIdx.x & 63;
    int l = lane & 15;
    int rowInWave = lane >> 4;
    int wave = blockIdx.x * 4 + (threadIdx.x >> 6);
    int row = wave * 4 + rowInWave;
    const float* xr = x + (size_t)row * D_DIM;
    float B[4];
#pragma unroll
    for (int b = 0; b < 4; ++b) {
        const float* a = xr + b * 128;
        float r[8];
#pragma unroll
        for (int j = 0; j < 8; ++j) {
            float v = a[j * 16 + l];
            r[j] = v * v;
        }
        float V = ((r[0] + r[1]) + (r[2] + r[3])) + ((r[4] + r[5]) + (r[6] + r[7]));
        float T1 = V + __shfl_xor(V, 8);
        float T2 = T1 + __shfl_xor(T1, 4);
        float U  = T2 + __shfl_xor(T2, 2);
        B[b] = U + __shfl_xor(U, 1);
    }
    float total = (B[0] + B[1]) + (B[2] + B[3]);
    if (l == 0) xnorm[row] = total;
}

// enorm = np.sum(e*e, axis=0): strictly sequential over d, no fma
__global__ __launch_bounds__(256) void k_enorm(const float* __restrict__ emb,
                                               float* __restrict__ enorm) {
#pragma clang fp contract(off)
    int k = blockIdx.x * 256 + threadIdx.x;
    float v = emb[k];
    float acc = v * v;
    for (int d = 1; d < D_DIM; ++d) {
        float u = emb[(size_t)d * K_CODES + k];
        acc = acc + u * u;
    }
    enorm[k] = acc;
}

// Fused GEMM + argmin. 128x128 tile, 256 threads, 8x8 micro-tile.
// A tile in LDS with XOR-d group swizzle (2-way max conflicts); B tile
// double-buffered, staged by global_load_lds issued AFTER the barrier so
// vmcnt(0) barrier drains see already-completed loads. Per-(row,col) fp32
// FMA chain is strictly d-ascending -> bitwise equal to numpy sgemm chain.
__global__ __launch_bounds__(256, 3) void k_argmin(const float* __restrict__ x,
                                                   const float* __restrict__ emb,
                                                   const float* __restrict__ xnorm,
                                                   const float* __restrict__ enorm,
                                                   unsigned long long* __restrict__ keys) {
    // As element (d,m) stored at d*128 + (((m>>2)^d)<<2) + (m&3)
    __shared__ float As[16 * 128];
    __shared__ float Bs[2][16 * 128];
    const int tid = threadIdx.x;
    const int tx = tid & 15;   // col group: cols {4tx..4tx+3, 64+4tx..+3}
    const int ty = tid >> 4;   // row group: rows {4ty..4ty+3, 64+4ty..+3}
    const int rowBase = blockIdx.x * 128;
    const int colBase = blockIdx.y * 128;
    const int lane = tid & 63;
    const int wv = tid >> 6;

    float acc[8][8];
#pragma unroll
    for (int j = 0; j < 8; ++j)
#pragma unroll
        for (int i = 0; i < 8; ++i) acc[j][i] = 0.f;

    // A staging: thread loads float4 at row lr (and lr+64), d-offset ld4
    const int lr = tid >> 2;         // 0..63
    const int ld4 = (tid & 3) * 4;   // 0,4,8,12
    const float* gA0 = x + (size_t)(rowBase + lr) * D_DIM + ld4;
    const float* gA1 = gA0 + (size_t)64 * D_DIM;

    // B async staging: wave wv covers d rows {2wv,2wv+1} and {8+2wv,8+2wv+1}
    const int bd0 = 2 * wv;
    const float* gBbase = emb + (size_t)(bd0 + (lane >> 5)) * K_CODES + colBase + (lane & 31) * 4;

    // prime: async B chunk 0, prefetch A chunk 0
    async_cp16(gBbase, &Bs[0][bd0 * 128]);
    async_cp16(gBbase + (size_t)8 * K_CODES, &Bs[0][(8 + bd0) * 128]);
    float4 pa0 = *(const float4*)gA0;
    float4 pa1 = *(const float4*)gA1;

    const int sg = lr >> 2;   // store group base (m>>2 for row lr)
    const int sc = lr & 3;

    for (int c = 0; c < 32; ++c) {
        __syncthreads();  // all waves done reading As / other B buffer
        // store A tile (swizzled, 2-way max bank conflicts)
        {
            const float a0v[4] = {pa0.x, pa0.y, pa0.z, pa0.w};
            const float a1v[4] = {pa1.x, pa1.y, pa1.z, pa1.w};
#pragma unroll
            for (int i = 0; i < 4; ++i) {
                int d = ld4 + i;
                int idx = d * 128 + ((sg ^ d) << 2) + sc;
                As[idx] = a0v[i];        // row lr   (group sg)
                As[idx + 64] = a1v[i];   // row lr+64 (group 16+sg)
            }
        }
        __syncthreads();  // As visible; async B for this chunk long since landed
        if (c + 1 < 32) {
            const int dn = (c + 1) * 16;
            float* bdst = &Bs[(c + 1) & 1][0];
            async_cp16(gBbase + (size_t)dn * K_CODES, bdst + bd0 * 128);
            async_cp16(gBbase + (size_t)(dn + 8) * K_CODES, bdst + (8 + bd0) * 128);
            pa0 = *(const float4*)(gA0 + dn);
            pa1 = *(const float4*)(gA1 + dn);
        }
        const float* B = &Bs[c & 1][0];
#pragma unroll
        for (int d = 0; d < 16; ++d) {
            const float4 a0 = *(const float4*)&As[d * 128 + ((ty ^ d) << 2)];
            const float4 a1 = *(const float4*)&As[d * 128 + ((ty ^ d) << 2) + 64];
            const float4 b0 = *(const float4*)&B[d * 128 + (tx << 2)];
            const float4 b1 = *(const float4*)&B[d * 128 + (tx << 2) + 64];
            const float av[8] = {a0.x, a0.y, a0.z, a0.w, a1.x, a1.y, a1.z, a1.w};
            const float bv[8] = {b0.x, b0.y, b0.z, b0.w, b1.x, b1.y, b1.z, b1.w};
#pragma unroll
            for (int j = 0; j < 8; ++j)
#pragma unroll
                for (int i = 0; i < 8; ++i)
                    acc[j][i] = fmaf(av[j], bv[i], acc[j][i]);
        }
    }

    // epilogue: d = fl(fl(xnorm+enorm) - 2*acc); pack into orderable key
    float en[8];
    *(float4*)&en[0] = *(const float4*)&enorm[colBase + 4 * tx];
    *(float4*)&en[4] = *(const float4*)&enorm[colBase + 64 + 4 * tx];
#pragma unroll
    for (int j = 0; j < 8; ++j) {
        int row = rowBase + ((j < 4) ? (4 * ty + j) : (64 + 4 * ty + (j - 4)));
        float A = xnorm[row];
        unsigned long long best = ~0ull;
#pragma unroll
        for (int i = 0; i < 8; ++i) {
            int col = colBase + ((i < 4) ? (4 * tx + i) : (64 + 4 * tx + (i - 4)));
            float t1 = A + en[i];
            float dd = t1 - 2.0f * acc[j][i];  // 2*acc exact; single rounding
            unsigned u = __float_as_uint(dd);
            u = (u & 0x80000000u) ? ~u : (u | 0x80000000u);
            unsigned long long key = ((unsigned long long)u << 32) | (unsigned)col;
            best = key < best ? key : best;
        }
#pragma unroll
        for (int off = 8; off > 0; off >>= 1) {
            unsigned long long other = __shfl_xor(best, off, 16);
            best = other < best ? other : best;
        }
        if (tx == 0) atomicMin(&keys[row], best);
    }
}

// gather codes, STE output fl(x + fl(q-x)), per-block f32 loss partial
__global__ __launch_bounds__(256) void k_gather(const float* __restrict__ x,
                                                const float* __restrict__ embSrc,
                                                int embIsT,
                                                const unsigned long long* __restrict__ keys,
                                                float* __restrict__ out,
                                                float* __restrict__ partial) {
#pragma clang fp contract(off)
    int tid = threadIdx.x;
    int row = blockIdx.x * 2 + (tid >> 7);
    int d = (tid & 127) * 4;
    int idx = (int)(keys[row] & 0xFFFFFFFFull);
    float4 q;
    if (embIsT) {
        q = *(const float4*)&embSrc[(size_t)idx * D_DIM + d];
    } else {
        q.x = embSrc[(size_t)(d + 0) * K_CODES + idx];
        q.y = embSrc[(size_t)(d + 1) * K_CODES + idx];
        q.z = embSrc[(size_t)(d + 2) * K_CODES + idx];
        q.w = embSrc[(size_t)(d + 3) * K_CODES + idx];
    }
    float4 xv = *(const float4*)&x[(size_t)row * D_DIM + d];
    float d0 = q.x - xv.x, d1 = q.y - xv.y, d2 = q.z - xv.z, d3 = q.w - xv.w;
    float4 o;
    o.x = xv.x + d0; o.y = xv.y + d1; o.z = xv.z + d2; o.w = xv.w + d3;
    *(float4*)&out[(size_t)row * D_DIM + d] = o;
    float s = (d0 * d0 + d1 * d1) + (d2 * d2 + d3 * d3);
#pragma unroll
    for (int off = 32; off > 0; off >>= 1) s += __shfl_xor(s, off, 64);
    __shared__ float wsum[4];
    int lane = tid & 63, wvv = tid >> 6;
    if (lane == 0) wsum[wvv] = s;
    __syncthreads();
    if (tid == 0) partial[blockIdx.x] = (wsum[0] + wsum[1]) + (wsum[2] + wsum[3]);
}

__global__ __launch_bounds__(256) void k_reduce(const float* __restrict__ partial,
                                                float* __restrict__ out) {
    float s = 0.f;
    for (int i = threadIdx.x; i < 16384; i += 256) s += partial[i];
#pragma unroll
    for (int off = 32; off > 0; off >>= 1) s += __shfl_xor(s, off, 64);
    __shared__ float wsum[4];
    int lane = threadIdx.x & 63, wv = threadIdx.x >> 6;
    if (lane == 0) wsum[wv] = s;
    __syncthreads();
    if (threadIdx.x == 0) {
        float t = (wsum[0] + wsum[1]) + (wsum[2] + wsum[3]);
        float m = t / 16777216.f;               // mean((q-x)^2), N*D = 2^24
        out[(size_t)N_ROWS * D_DIM] = 0.25f * m + m;  // beta*m + m
    }
}

extern "C" void kernel_launch(void* const* d_in, const int* in_sizes, int n_in,
                              void* d_out, int out_size, void* d_ws, size_t ws_size,
                              hipStream_t stream) {
    const float* x = (const float*)d_in[0];
    const float* emb = (const float*)d_in[1];
    float* out = (float*)d_out;
    char* ws = (char*)d_ws;

    unsigned long long* keys = (unsigned long long*)(ws + WS_KEYS);
    float* xnorm = (float*)(ws + WS_XNORM);
    float* enorm = (float*)(ws + WS_ENORM);
    float* partial = (float*)(ws + WS_PART);
    float* embT = (float*)(ws + WS_EMBT);
    size_t need = WS_EMBT + (size_t)K_CODES * D_DIM * sizeof(float);
    int useT = (ws_size >= need) ? 1 : 0;

    hipLaunchKernelGGL(k_init, dim3(128), dim3(256), 0, stream, keys);
    if (useT)
        hipLaunchKernelGGL(k_transpose, dim3(K_CODES / 64, D_DIM / 64), dim3(256), 0, stream,
                           emb, embT);
    hipLaunchKernelGGL(k_xnorm, dim3(N_ROWS / 16), dim3(256), 0, stream, x, xnorm);
    hipLaunchKernelGGL(k_enorm, dim3(K_CODES / 256), dim3(256), 0, stream, emb, enorm);
    hipLaunchKernelGGL(k_argmin, dim3(N_ROWS / 128, K_CODES / 128), dim3(256), 0, stream,
                       x, emb, xnorm, enorm, keys);
    hipLaunchKernelGGL(k_gather, dim3(N_ROWS / 2), dim3(256), 0, stream,
                       x, useT ? embT : emb, useT, keys, out, partial);
    hipLaunchKernelGGL(k_reduce, dim3(1), dim3(256), 0, stream, partial, out);
}